// Round 17
// baseline (88.067 us; speedup 1.0000x reference)
//
#include <hip/hip_runtime.h>

#define NROWS 8192
#define NCOLS 4096
#define LAMB  0.1
#define NBUCK 2048
#define NBLK  1024

typedef unsigned int u32;
typedef unsigned long long u64;

// ---------------------------------------------------------------------------
// fast f64 reciprocal: f32 seed + 2 Newton steps (~1 ulp, no f64 divide)
// ---------------------------------------------------------------------------
__device__ __forceinline__ double fastrcp(double x) {
    double r = (double)(1.0f / (float)x);
    r = r * (2.0 - x * r);
    r = r * (2.0 - x * r);
    return r;
}

// ---------------------------------------------------------------------------
// FUSED v2: 1024 blocks x 1024 threads.
// Phase A: each block = 4 independent 256-thread row-groups (R10's exact
//   per-row access pattern), 2 rows per group -> 8 rows/block. err written
//   via AGENT-scope atomic stores. LDS ~50 KB -> 2 blocks/CU (32 waves/CU,
//   same residency as R10's 8x256). This fixes both R12 mistakes
//   (wave-per-row mapping + 76.8 KB LDS).
// Ticket: barrier -> ACQ_REL fetch_add (R12's validated recipe); last block
//   runs the tail, all other blocks exit -> no second dispatch boundary.
// Tail (1 block): AGENT re-read of err, bucket sort + exact rank IN PLACE
//   (R15 logic), then obj: argmax h(k) = cs^2/k + (total-cs)^2/(n-k)
//   (== argmin (Sw1+Sw2)/Sb), out[0] = cs/T + LAMB*optObj.
// ---------------------------------------------------------------------------
__global__ __launch_bounds__(1024) void fused_kernel(const float* __restrict__ inp,
                                                     const float* __restrict__ tgt,
                                                     float* err, u32* counter,
                                                     float* __restrict__ out) {
    const int N = NROWS;
    __shared__ u32 bufB[NROWS];            // 32 KB (tail: scattered -> sorted)
    __shared__ u32 hist[NBUCK];            // 8 KB
    __shared__ u32 base2[NBUCK];           // 8 KB
    __shared__ float ws[32];               // phase A: 4 groups x 2 rows x 4 waves
    __shared__ u32 sMin[16], sMax[16], saux[16];
    __shared__ double auxX[16], auxT2[16], redH[16], redCs[16];
    __shared__ int    redIdx[16];
    __shared__ int    amLast;

    const int tid  = threadIdx.x;
    const int lane = tid & 63, wv = tid >> 6;
    const int gid  = tid >> 8;             // row-group 0..3
    const int t256 = tid & 255;
    const int wvg  = (tid >> 6) & 3;       // wave within group

    // ================= phase A: rowerr, R10 access pattern =================
    const int row0 = blockIdx.x * 8 + gid * 2;
    float accr[2];
#pragma unroll
    for (int rr = 0; rr < 2; ++rr) {
        const float4* a = reinterpret_cast<const float4*>(inp + (size_t)(row0 + rr) * NCOLS);
        const float4* b = reinterpret_cast<const float4*>(tgt + (size_t)(row0 + rr) * NCOLS);
        float acc = 0.f;
#pragma unroll
        for (int c = 0; c < 4; ++c) {
            const float4 va = a[t256 + c * 256];
            const float4 vb = b[t256 + c * 256];
            const float dx = va.x - vb.x;
            const float dy = va.y - vb.y;
            const float dz = va.z - vb.z;
            const float dw = va.w - vb.w;
            acc += dx * dx + dy * dy + dz * dz + dw * dw;
        }
#pragma unroll
        for (int off = 32; off > 0; off >>= 1) acc += __shfl_down(acc, off, 64);
        accr[rr] = acc;
    }
    if (lane == 0) {
        ws[gid * 8 + wvg]     = accr[0];
        ws[gid * 8 + 4 + wvg] = accr[1];
    }
    __syncthreads();
    if (t256 == 0) {
        const float v0 = (ws[gid*8+0] + ws[gid*8+1]) + (ws[gid*8+2] + ws[gid*8+3]);
        const float v1 = (ws[gid*8+4] + ws[gid*8+5]) + (ws[gid*8+6] + ws[gid*8+7]);
        __hip_atomic_store(&err[row0],     v0, __ATOMIC_RELAXED, __HIP_MEMORY_SCOPE_AGENT);
        __hip_atomic_store(&err[row0 + 1], v1, __ATOMIC_RELAXED, __HIP_MEMORY_SCOPE_AGENT);
    }

    // ================= ticket (R12's validated recipe) =====================
    __syncthreads();   // all 4 groups' stores issued & drained before ticket
    if (tid == 0) {
        const u32 old = __hip_atomic_fetch_add(counter, 1u, __ATOMIC_ACQ_REL,
                                               __HIP_MEMORY_SCOPE_AGENT);
        amLast = (old == (u32)(NBLK - 1));
    }
    __syncthreads();
    if (!amLast) return;

    // ================= tail: stage err + min/max ===========================
    u32 bits[8];
    u32 mn = 0xFFFFFFFFu, mx = 0u;
#pragma unroll
    for (int k = 0; k < 8; ++k) {
        const float v = __hip_atomic_load(&err[tid + k * 1024], __ATOMIC_RELAXED,
                                          __HIP_MEMORY_SCOPE_AGENT);
        bits[k] = __float_as_uint(v);
        mn = min(mn, bits[k]);
        mx = max(mx, bits[k]);
    }
#pragma unroll
    for (int off = 32; off > 0; off >>= 1) {
        mn = min(mn, (u32)__shfl_xor((int)mn, off, 64));
        mx = max(mx, (u32)__shfl_xor((int)mx, off, 64));
    }
    if (lane == 0) { sMin[wv] = mn; sMax[wv] = mx; }

    hist[tid] = 0;
    hist[tid + 1024] = 0;
    __syncthreads();

    u32 minb = sMin[0], maxb = sMax[0];
#pragma unroll
    for (int w = 1; w < 16; ++w) { minb = min(minb, sMin[w]); maxb = max(maxb, sMax[w]); }
    const u32 range = maxb - minb;
    const int nbits = 32 - __clz(range | 1u);          // >= 1
    const int shift = (nbits > 11) ? (nbits - 11) : 0; // bucket < 2048

    u32 bk[8];
#pragma unroll
    for (int k = 0; k < 8; ++k) {
        bits[k] -= minb;
        bk[k] = bits[k] >> shift;
        atomicAdd(&hist[bk[k]], 1u);
    }
    __syncthreads();

    // ---- exclusive scan of 2048 counts (2 per thread) ----
    const u32 c0 = hist[2 * tid], c1 = hist[2 * tid + 1];
    const u32 tsum = c0 + c1;
    u32 incl = tsum;
#pragma unroll
    for (int off = 1; off < 64; off <<= 1) {
        const u32 t = __shfl_up(incl, off, 64);
        if (lane >= off) incl += t;
    }
    if (lane == 63) saux[wv] = incl;
    __syncthreads();
    u32 add = 0;
#pragma unroll
    for (int w = 0; w < 16; ++w) if (w < wv) add += saux[w];
    const u32 excl = add + incl - tsum;
    base2[2 * tid] = excl;           base2[2 * tid + 1] = excl + c0;
    hist[2 * tid]  = excl;           hist[2 * tid + 1]  = excl + c0;   // cursors
    __syncthreads();

    // ---- scatter; atomic cursor return = tie-break order within bucket ----
    u32 myq[8];
#pragma unroll
    for (int k = 0; k < 8; ++k) {
        const u32 p = atomicAdd(&hist[bk[k]], 1u);
        myq[k] = p - base2[bk[k]];
        bufB[p] = bits[k];
    }
    __syncthreads();                       // hist[b] is now segment END

    // ---- exact rank within bucket (reads only) ----
    u32 pos[8];
#pragma unroll
    for (int k = 0; k < 8; ++k) {
        const u32 s = base2[bk[k]];
        const u32 e = hist[bk[k]];
        const u32 ki = bits[k];
        u32 r = 0;
        for (u32 q = 0; q < e - s; ++q) {
            const u32 v = bufB[s + q];
            r += (v < ki || (v == ki && q < myq[k])) ? 1u : 0u;
        }
        pos[k] = s + r;
    }
    __syncthreads();                       // all rank reads complete

    // ---- in-place sorted write ----
#pragma unroll
    for (int k = 0; k < 8; ++k) bufB[pos[k]] = bits[k];
    __syncthreads();                       // bufB fully sorted (biased keys)

    // ================= obj phase ==========================================
    float v[8];
#pragma unroll
    for (int r = 0; r < 8; ++r) v[r] = __uint_as_float(bufB[(tid << 3) + r] + minb);

    double sx = 0.0, sx2 = 0.0;
#pragma unroll
    for (int r = 0; r < 8; ++r) {
        sx  += (double)v[r];
        sx2 += (double)v[r] * (double)v[r];
    }

    double ix = sx;
#pragma unroll
    for (int off = 1; off < 64; off <<= 1) {
        double t1 = __shfl_up(ix, off, 64);
        if (lane >= off) ix += t1;
    }
    double t2 = sx2;
#pragma unroll
    for (int off = 32; off > 0; off >>= 1) t2 += __shfl_xor(t2, off, 64);

    if (lane == 63) auxX[wv]  = ix;
    if (lane == 0)  auxT2[wv] = t2;
    __syncthreads();

    double wOff1 = 0.0, total1 = 0.0, total2 = 0.0;
#pragma unroll
    for (int w = 0; w < 16; ++w) {
        const double a1 = auxX[w];
        if (w < wv) wOff1 += a1;
        total1 += a1;
        total2 += auxT2[w];
    }
    const double exc1 = wOff1 + (ix - sx);
    const double nf = (double)N;

    double run1 = exc1;
    double bestH = -1e300, bestCs = 0.0;
    int bestIdx = N;
#pragma unroll
    for (int r = 0; r < 8; ++r) {
        const int idx = (tid << 3) + r;
        run1 += (double)v[r];
        if (idx < N - 1) {
            const double kf  = (double)(idx + 1);
            const double rem = total1 - run1;
            const double h   = run1 * run1 * fastrcp(kf) +
                               rem  * rem  * fastrcp(nf - kf);
            if (h > bestH) { bestH = h; bestIdx = idx; bestCs = run1; }
        }
    }

#pragma unroll
    for (int off = 32; off > 0; off >>= 1) {
        const double oH   = __shfl_down(bestH, off, 64);
        const int    oIdx = __shfl_down(bestIdx, off, 64);
        const double oCs  = __shfl_down(bestCs, off, 64);
        if (oH > bestH || (oH == bestH && oIdx < bestIdx)) {
            bestH = oH; bestIdx = oIdx; bestCs = oCs;
        }
    }
    if (lane == 0) { redH[wv] = bestH; redIdx[wv] = bestIdx; redCs[wv] = bestCs; }
    __syncthreads();

    if (tid == 0) {
        double bH = redH[0], bCs = redCs[0];
        int bIdx = redIdx[0];
        for (int w = 1; w < 16; ++w) {
            if (redH[w] > bH || (redH[w] == bH && redIdx[w] < bIdx)) {
                bH = redH[w]; bIdx = redIdx[w]; bCs = redCs[w];
            }
        }
        const double Sb     = total2 - total1 * total1 / nf;
        const double optObj = (total2 - bH) / Sb;
        const double T      = (double)(bIdx + 1);
        out[0] = (float)(bCs / T + LAMB * optObj);
    }
}

// ---------------------------------------------------------------------------
extern "C" void kernel_launch(void* const* d_in, const int* in_sizes, int n_in,
                              void* d_out, int out_size, void* d_ws, size_t ws_size,
                              hipStream_t stream) {
    const float* inp = (const float*)d_in[0];
    const float* tgt = (const float*)d_in[1];
    float* errbuf  = (float*)d_ws;                      // 8192 f32 = 32 KB
    u32*   counter = (u32*)((char*)d_ws + NROWS * 4);   // 4 B ticket

    hipMemsetAsync(counter, 0, 4, stream);              // graph-legal init
    fused_kernel<<<NBLK, 1024, 0, stream>>>(inp, tgt, errbuf, counter,
                                            (float*)d_out);
}

// Round 18
// 61.394 us; speedup vs baseline: 1.4344x; 1.4344x over previous
//
#include <hip/hip_runtime.h>

#define NROWS 8192
#define NCOLS 4096
#define LAMB  0.1
#define NBUCK 4096

typedef unsigned int u32;
typedef unsigned long long u64;

// ---------------------------------------------------------------------------
// Kernel 1: per-row squared error sum. ONE 256-THREAD BLOCK PER ROW.
// Byte-identical to R10/R13 (best measured; ~41 us in-bench, warm L3).
// ---------------------------------------------------------------------------
__global__ __launch_bounds__(256) void rowerr_kernel(const float* __restrict__ inp,
                                                     const float* __restrict__ tgt,
                                                     float* __restrict__ err) {
    const int row = blockIdx.x;
    const float4* a = reinterpret_cast<const float4*>(inp + (size_t)row * NCOLS);
    const float4* b = reinterpret_cast<const float4*>(tgt + (size_t)row * NCOLS);
    const int t = threadIdx.x;

    float acc = 0.f;
#pragma unroll
    for (int c = 0; c < 4; ++c) {
        float4 va = a[t + c * 256];
        float4 vb = b[t + c * 256];
        float dx = va.x - vb.x;
        float dy = va.y - vb.y;
        float dz = va.z - vb.z;
        float dw = va.w - vb.w;
        acc += dx * dx + dy * dy + dz * dz + dw * dw;
    }

#pragma unroll
    for (int off = 32; off > 0; off >>= 1) acc += __shfl_down(acc, off, 64);

    __shared__ float ws[4];
    const int lane = t & 63, wv = t >> 6;
    if (lane == 0) ws[wv] = acc;
    __syncthreads();
    if (t == 0) err[row] = ws[0] + ws[1] + ws[2] + ws[3];
}

// ---------------------------------------------------------------------------
// fast f64 reciprocal: f32 seed + 2 Newton steps (~1 ulp, no f64 divide)
// ---------------------------------------------------------------------------
__device__ __forceinline__ double fastrcp(double x) {
    double r = (double)(1.0f / (float)x);
    r = r * (2.0 - x * r);
    r = r * (2.0 - x * r);
    return r;
}

// ---------------------------------------------------------------------------
// Kernel 2: single block, 1024 threads. Bucket sort + exact rank, v3:
//   - ONE atomic round: hist atomicAdd's return value = arrival sequence
//     within bucket (myq). Scatter is then a PLAIN LDS write to
//     base2[bk]+myq. (v2 did hist atomics AND cursor atomics: 2x cost.)
//   - 4096 buckets (avg 2 elems) halves the rank-loop reads vs 2048.
//   1. float4-stage err -> regs; min/max via shuffle
//   2. single LDS-atomic histogram round (returns = in-bucket seq)
//   3. exclusive scan of 4096 counts (4/thread); hist stays = counts
//   4. plain-write scatter to base2[bk]+myq
//   5. exact in-bucket rank (reads only) -> barrier -> in-place write
//   6. obj: f64 scan of cs, total of cs2, argmax of
//      h(k) = cs^2/k + (total-cs)^2/(n-k)   (== argmin (Sw1+Sw2)/Sb)
// Exact permutation for any input (degenerate = slower, still exact).
// ---------------------------------------------------------------------------
__global__ __launch_bounds__(1024) void drae_kernel(const float* __restrict__ err,
                                                    float* __restrict__ out) {
    const int N = NROWS;
    __shared__ u32 bufB[NROWS];            // 32 KB  scattered -> sorted (in place)
    __shared__ u32 hist[NBUCK];            // 16 KB  counts (never overwritten)
    __shared__ u32 base2[NBUCK];           // 16 KB  segment starts
    __shared__ u32 sMin[16], sMax[16], saux[16];
    __shared__ double auxX[16], auxT2[16], redH[16], redCs[16];
    __shared__ int    redIdx[16];

    const int tid  = threadIdx.x;
    const int lane = tid & 63, wv = tid >> 6;

    // ---- stage err as float4 -> regs; min/max; zero hist ----
    u32 bits[8];
    {
        const float4* e4 = reinterpret_cast<const float4*>(err);
        const float4 f0 = e4[tid];
        const float4 f1 = e4[tid + 1024];
        bits[0] = __float_as_uint(f0.x);
        bits[1] = __float_as_uint(f0.y);
        bits[2] = __float_as_uint(f0.z);
        bits[3] = __float_as_uint(f0.w);
        bits[4] = __float_as_uint(f1.x);
        bits[5] = __float_as_uint(f1.y);
        bits[6] = __float_as_uint(f1.z);
        bits[7] = __float_as_uint(f1.w);
    }
    u32 mn = 0xFFFFFFFFu, mx = 0u;
#pragma unroll
    for (int k = 0; k < 8; ++k) { mn = min(mn, bits[k]); mx = max(mx, bits[k]); }
#pragma unroll
    for (int off = 32; off > 0; off >>= 1) {
        mn = min(mn, (u32)__shfl_xor((int)mn, off, 64));
        mx = max(mx, (u32)__shfl_xor((int)mx, off, 64));
    }
    if (lane == 0) { sMin[wv] = mn; sMax[wv] = mx; }

#pragma unroll
    for (int k = 0; k < 4; ++k) hist[tid + k * 1024] = 0;
    __syncthreads();

    u32 minb = sMin[0], maxb = sMax[0];
#pragma unroll
    for (int w = 1; w < 16; ++w) { minb = min(minb, sMin[w]); maxb = max(maxb, sMax[w]); }
    const u32 range = maxb - minb;
    const int nbits = 32 - __clz(range | 1u);          // >= 1
    const int shift = (nbits > 12) ? (nbits - 12) : 0; // bucket < 4096

    // ---- single atomic round: count AND capture in-bucket sequence ----
    u32 bk[8], myq[8];
#pragma unroll
    for (int k = 0; k < 8; ++k) {
        bits[k] -= minb;
        bk[k] = bits[k] >> shift;
        myq[k] = atomicAdd(&hist[bk[k]], 1u);          // return = my seq in bucket
    }
    __syncthreads();

    // ---- exclusive scan of 4096 counts (4 per thread); hist stays counts ----
    const u32 c0 = hist[4 * tid],     c1 = hist[4 * tid + 1];
    const u32 c2 = hist[4 * tid + 2], c3 = hist[4 * tid + 3];
    const u32 tsum = (c0 + c1) + (c2 + c3);
    u32 incl = tsum;
#pragma unroll
    for (int off = 1; off < 64; off <<= 1) {
        const u32 t = __shfl_up(incl, off, 64);
        if (lane >= off) incl += t;
    }
    if (lane == 63) saux[wv] = incl;
    __syncthreads();
    u32 add = 0;
#pragma unroll
    for (int w = 0; w < 16; ++w) if (w < wv) add += saux[w];
    const u32 excl = add + incl - tsum;
    base2[4 * tid]     = excl;
    base2[4 * tid + 1] = excl + c0;
    base2[4 * tid + 2] = excl + c0 + c1;
    base2[4 * tid + 3] = excl + c0 + c1 + c2;
    __syncthreads();

    // ---- plain-write scatter (no atomics: slot = base + seq) ----
#pragma unroll
    for (int k = 0; k < 8; ++k) bufB[base2[bk[k]] + myq[k]] = bits[k];
    __syncthreads();

    // ---- exact rank within bucket (reads only; avg 2 elems/bucket) ----
    u32 pos[8];
#pragma unroll
    for (int k = 0; k < 8; ++k) {
        const u32 s = base2[bk[k]];
        const u32 c = hist[bk[k]];
        const u32 ki = bits[k];
        u32 r = 0;
        for (u32 q = 0; q < c; ++q) {
            const u32 v = bufB[s + q];
            r += (v < ki || (v == ki && q < myq[k])) ? 1u : 0u;
        }
        pos[k] = s + r;
    }
    __syncthreads();                       // all rank reads complete

    // ---- in-place sorted write ----
#pragma unroll
    for (int k = 0; k < 8; ++k) bufB[pos[k]] = bits[k];
    __syncthreads();                       // bufB fully sorted (biased keys)

    // ================= obj phase ==========================================
    float v[8];
#pragma unroll
    for (int r = 0; r < 8; ++r) v[r] = __uint_as_float(bufB[(tid << 3) + r] + minb);

    double sx = 0.0, sx2 = 0.0;
#pragma unroll
    for (int r = 0; r < 8; ++r) {
        sx  += (double)v[r];
        sx2 += (double)v[r] * (double)v[r];
    }

    // wave inclusive scan of sx; wave total of sx2
    double ix = sx;
#pragma unroll
    for (int off = 1; off < 64; off <<= 1) {
        double t1 = __shfl_up(ix, off, 64);
        if (lane >= off) ix += t1;
    }
    double t2 = sx2;
#pragma unroll
    for (int off = 32; off > 0; off >>= 1) t2 += __shfl_xor(t2, off, 64);

    if (lane == 63) auxX[wv]  = ix;
    if (lane == 0)  auxT2[wv] = t2;
    __syncthreads();

    double wOff1 = 0.0, total1 = 0.0, total2 = 0.0;
#pragma unroll
    for (int w = 0; w < 16; ++w) {
        const double a1 = auxX[w];
        if (w < wv) wOff1 += a1;
        total1 += a1;
        total2 += auxT2[w];
    }
    const double exc1 = wOff1 + (ix - sx);
    const double nf = (double)N;

    // on-the-fly h(k) + local argmax (== argmin obj), first index on ties
    double run1 = exc1;
    double bestH = -1e300, bestCs = 0.0;
    int bestIdx = N;
#pragma unroll
    for (int r = 0; r < 8; ++r) {
        const int idx = (tid << 3) + r;
        run1 += (double)v[r];
        if (idx < N - 1) {
            const double kf  = (double)(idx + 1);
            const double rem = total1 - run1;
            const double h   = run1 * run1 * fastrcp(kf) +
                               rem  * rem  * fastrcp(nf - kf);
            if (h > bestH) { bestH = h; bestIdx = idx; bestCs = run1; }
        }
    }

    // wave argmax reduce (max h, first index on ties)
#pragma unroll
    for (int off = 32; off > 0; off >>= 1) {
        const double oH   = __shfl_down(bestH, off, 64);
        const int    oIdx = __shfl_down(bestIdx, off, 64);
        const double oCs  = __shfl_down(bestCs, off, 64);
        if (oH > bestH || (oH == bestH && oIdx < bestIdx)) {
            bestH = oH; bestIdx = oIdx; bestCs = oCs;
        }
    }
    if (lane == 0) { redH[wv] = bestH; redIdx[wv] = bestIdx; redCs[wv] = bestCs; }
    __syncthreads();

    if (tid == 0) {
        double bH = redH[0], bCs = redCs[0];
        int bIdx = redIdx[0];
        for (int w = 1; w < 16; ++w) {
            if (redH[w] > bH || (redH[w] == bH && redIdx[w] < bIdx)) {
                bH = redH[w]; bIdx = redIdx[w]; bCs = redCs[w];
            }
        }
        const double Sb     = total2 - total1 * total1 / nf;
        const double optObj = (total2 - bH) / Sb;
        const double T      = (double)(bIdx + 1);
        out[0] = (float)(bCs / T + LAMB * optObj);
    }
}

// ---------------------------------------------------------------------------
extern "C" void kernel_launch(void* const* d_in, const int* in_sizes, int n_in,
                              void* d_out, int out_size, void* d_ws, size_t ws_size,
                              hipStream_t stream) {
    const float* inp = (const float*)d_in[0];
    const float* tgt = (const float*)d_in[1];
    float* errbuf = (float*)d_ws;   // 8192 f32 = 32 KB scratch

    rowerr_kernel<<<NROWS, 256, 0, stream>>>(inp, tgt, errbuf);
    drae_kernel<<<1, 1024, 0, stream>>>(errbuf, (float*)d_out);
}